// Round 11
// baseline (423.539 us; speedup 1.0000x reference)
//
#include <hip/hip_runtime.h>
#include <math.h>
#include <type_traits>

typedef __bf16 bf16;
typedef __attribute__((ext_vector_type(8))) __bf16 bf16x8;
typedef __attribute__((ext_vector_type(4))) float f32x4;
typedef __attribute__((ext_vector_type(16))) float f32x16;

#define SEQ 2048
#define DM 1024
#define NH 16
#define HD 64
#define BATCH 4

#define NEG_BIG (-1e30f)
// softmax in exp2 domain: p = 2^(s * (1/8) * log2(e))
#define SCALE_L2E 0.18033688011f

__device__ inline bf16x8 pack_bf16x8(f32x4 x0, f32x4 x1) {
  bf16x8 r;
  r[0] = (bf16)x0[0]; r[1] = (bf16)x0[1]; r[2] = (bf16)x0[2]; r[3] = (bf16)x0[3];
  r[4] = (bf16)x1[0]; r[5] = (bf16)x1[1]; r[6] = (bf16)x1[2]; r[7] = (bf16)x1[3];
  return r;
}

// async global->LDS DMA, 16 B per lane; LDS dest is wave-uniform base, HW
// writes lane i at base + i*16 (m97 pattern).
__device__ inline void async_copy16(const bf16* g, bf16* l) {
  __builtin_amdgcn_global_load_lds(
      (const __attribute__((address_space(1))) unsigned int*)g,
      (__attribute__((address_space(3))) unsigned int*)l, 16, 0, 0);
}

// ---------------------------------------------------------------------------
// Weight transpose + f32->bf16 convert: Wt[n][k] = (bf16)W[k][n], 1024x1024.
// ---------------------------------------------------------------------------
__global__ __launch_bounds__(256) void transpose_w_kernel(
    const float* __restrict__ Wq, const float* __restrict__ Wk,
    const float* __restrict__ Wv, const float* __restrict__ Wo,
    bf16* __restrict__ Tq, bf16* __restrict__ Tk,
    bf16* __restrict__ Tv, bf16* __restrict__ To) {
  __shared__ bf16 tile[64 * 66];
  int z = blockIdx.z;
  const float* src = (z == 0) ? Wq : (z == 1) ? Wk : (z == 2) ? Wv : Wo;
  bf16* dst = (z == 0) ? Tq : (z == 1) ? Tk : (z == 2) ? Tv : To;
  int n0 = blockIdx.x * 64, k0 = blockIdx.y * 64;
  int t = threadIdx.x;
  int c = t & 63, rr = t >> 6;
#pragma unroll
  for (int i = 0; i < 16; i++) {
    int k = i * 4 + rr;
    tile[k * 66 + c] = (bf16)src[(size_t)(k0 + k) * DM + n0 + c];
  }
  __syncthreads();
#pragma unroll
  for (int i = 0; i < 16; i++) {
    int n = i * 4 + rr;
    dst[(size_t)(n0 + n) * DM + k0 + c] = tile[c * 66 + n];
  }
}

// ---------------------------------------------------------------------------
// FUSED QKV GEMM (r10, measured 139us for all three projections = 371 TF):
// reads f32 activations directly (cvt folded into A reg-staging, T14
// ordering), B via global_load_lds, LDS double-buffer.
// z<2 -> compact per-head C [B,H,S,64]; z==2 -> V^T C [B,H,64,S].
// ---------------------------------------------------------------------------
__global__ __launch_bounds__(256) void qkv_gemm_kernel(
    const float* __restrict__ Aq, const float* __restrict__ Ak,
    const float* __restrict__ Av, const bf16* __restrict__ Tq,
    const bf16* __restrict__ Tk, const bf16* __restrict__ Tv,
    const float* __restrict__ bq, const float* __restrict__ bk,
    const float* __restrict__ bv, bf16* __restrict__ Cq,
    bf16* __restrict__ Ck, bf16* __restrict__ Cv) {
  int z = blockIdx.z;
  const float* A = (z == 0) ? Aq : (z == 1) ? Ak : Av;
  const bf16* Bt = (z == 0) ? Tq : (z == 1) ? Tk : Tv;
  const float* bias = (z == 0) ? bq : (z == 1) ? bk : bv;
  bf16* C = (z == 0) ? Cq : (z == 1) ? Ck : Cv;

  __shared__ bf16 As[2][128 * 32];
  __shared__ bf16 Bs[2][128 * 32];
  int m0 = blockIdx.x * 128, n0 = blockIdx.y * 128;
  int t = threadIdx.x;
  int wave = t >> 6, lane = t & 63, lr = lane & 15, lq = lane >> 4;
  int wm = (wave & 1) * 64, wn = (wave >> 1) * 64;

  f32x4 acc[4][4];
#pragma unroll
  for (int i = 0; i < 4; i++)
#pragma unroll
    for (int j = 0; j < 4; j++) acc[i][j] = (f32x4){0.f, 0.f, 0.f, 0.f};

  int arow = t >> 2;
  int acolf = (t & 3) * 8;
  const float* gA = A + (size_t)(m0 + arow) * DM + acolf;
  const float* gA2 = gA + (size_t)64 * DM;
  f32x4 ar[2][2];

  auto loadA = [&](int k0) {
    ar[0][0] = *(const f32x4*)(gA + k0);
    ar[0][1] = *(const f32x4*)(gA + k0 + 4);
    ar[1][0] = *(const f32x4*)(gA2 + k0);
    ar[1][1] = *(const f32x4*)(gA2 + k0 + 4);
  };
  auto cvtwriteA = [&](int buf) {
    *(bf16x8*)&As[buf][arow * 32 + acolf] = pack_bf16x8(ar[0][0], ar[0][1]);
    *(bf16x8*)&As[buf][(arow + 64) * 32 + acolf] =
        pack_bf16x8(ar[1][0], ar[1][1]);
  };

  int srow = wave * 32 + (lane >> 2);
  int skc = lane & 3;
  const bf16* gB0 = Bt + (size_t)(n0 + srow) * DM + skc * 8;
  const bf16* gB1 = gB0 + (size_t)16 * DM;
  int oB0 = (wave * 128) * 8;
  int oB1 = (wave * 128 + 64) * 8;
  auto stageB = [&](int buf) {
    async_copy16(gB0, &Bs[buf][oB0]);
    async_copy16(gB1, &Bs[buf][oB1]);
    gB0 += 32; gB1 += 32;
  };

  loadA(0);
  stageB(0);
  cvtwriteA(0);
  __syncthreads();

  int cur = 0;
  for (int k0 = 0; k0 < DM; k0 += 32) {
    bool more = (k0 + 32 < DM);
    if (more) {
      loadA(k0 + 32);
      stageB(cur ^ 1);
    }

    bf16x8 af[4], bfr[4];
#pragma unroll
    for (int i = 0; i < 4; i++)
      af[i] = *(const bf16x8*)&As[cur][(wm + i * 16 + lr) * 32 + lq * 8];
#pragma unroll
    for (int j = 0; j < 4; j++)
      bfr[j] = *(const bf16x8*)&Bs[cur][(wn + j * 16 + lr) * 32 + lq * 8];
    __builtin_amdgcn_s_setprio(1);
#pragma unroll
    for (int i = 0; i < 4; i++)
#pragma unroll
      for (int j = 0; j < 4; j++)
        acc[i][j] = __builtin_amdgcn_mfma_f32_16x16x32_bf16(af[i], bfr[j],
                                                            acc[i][j], 0, 0, 0);
    __builtin_amdgcn_s_setprio(0);
    if (more) cvtwriteA(cur ^ 1);
    __syncthreads();
    cur ^= 1;
  }

#pragma unroll
  for (int j = 0; j < 4; j++) {
    int col = n0 + wn + j * 16 + lr;
    float bv2 = bias[col];
#pragma unroll
    for (int i = 0; i < 4; i++) {
      int row0 = m0 + wm + i * 16 + lq * 4;
#pragma unroll
      for (int r = 0; r < 4; r++) {
        int row = row0 + r;
        float v = acc[i][j][r] + bv2;
        int b = row >> 11, s = row & 2047, h = col >> 6, d = col & 63;
        if (z < 2) {
          C[((size_t)(b * NH + h) * SEQ + s) * HD + d] = (bf16)v;
        } else {
          C[((size_t)(b * NH + h) * HD + d) * SEQ + s] = (bf16)v;
        }
      }
    }
  }
}

// ---------------------------------------------------------------------------
// Output GEMM (bf16 A), r8 BN=128 dbuf version. MODE 0: C[row*1024+col] f32.
// ---------------------------------------------------------------------------
template <typename CT, int MODE>
__global__ __launch_bounds__(256) void gemm_bias_kernel(
    const bf16* __restrict__ A, const bf16* __restrict__ Bt,
    const float* __restrict__ bias, CT* __restrict__ C) {
  __shared__ bf16 As[2][128 * 32];
  __shared__ bf16 Bs[2][128 * 32];
  int m0 = blockIdx.x * 128, n0 = blockIdx.y * 128;
  int t = threadIdx.x;
  int wave = t >> 6, lane = t & 63, lr = lane & 15, lq = lane >> 4;
  int wm = (wave & 1) * 64, wn = (wave >> 1) * 64;

  f32x4 acc[4][4];
#pragma unroll
  for (int i = 0; i < 4; i++)
#pragma unroll
    for (int j = 0; j < 4; j++) acc[i][j] = (f32x4){0.f, 0.f, 0.f, 0.f};

  int srow = wave * 32 + (lane >> 2);
  int skc = lane & 3;
  const bf16* gA0 = A + (size_t)(m0 + srow) * DM + skc * 8;
  const bf16* gA1 = gA0 + (size_t)16 * DM;
  const bf16* gB0 = Bt + (size_t)(n0 + srow) * DM + skc * 8;
  const bf16* gB1 = gB0 + (size_t)16 * DM;
  int oA0 = (wave * 128) * 8;
  int oA1 = (wave * 128 + 64) * 8;

  auto stage = [&](int buf) {
    async_copy16(gA0, &As[buf][oA0]);
    async_copy16(gA1, &As[buf][oA1]);
    async_copy16(gB0, &Bs[buf][oA0]);
    async_copy16(gB1, &Bs[buf][oA1]);
    gA0 += 32; gA1 += 32; gB0 += 32; gB1 += 32;
  };

  stage(0);
  __syncthreads();
  int cur = 0;
  for (int k0 = 0; k0 < DM; k0 += 32) {
    if (k0 + 32 < DM) stage(cur ^ 1);

    bf16x8 af[4], bfr[4];
#pragma unroll
    for (int i = 0; i < 4; i++)
      af[i] = *(const bf16x8*)&As[cur][(wm + i * 16 + lr) * 32 + lq * 8];
#pragma unroll
    for (int j = 0; j < 4; j++)
      bfr[j] = *(const bf16x8*)&Bs[cur][(wn + j * 16 + lr) * 32 + lq * 8];
    __builtin_amdgcn_s_setprio(1);
#pragma unroll
    for (int i = 0; i < 4; i++)
#pragma unroll
      for (int j = 0; j < 4; j++)
        acc[i][j] = __builtin_amdgcn_mfma_f32_16x16x32_bf16(af[i], bfr[j],
                                                            acc[i][j], 0, 0, 0);
    __builtin_amdgcn_s_setprio(0);
    __syncthreads();
    cur ^= 1;
  }

#pragma unroll
  for (int j = 0; j < 4; j++) {
    int col = n0 + wn + j * 16 + lr;
    float bv = bias[col];
#pragma unroll
    for (int i = 0; i < 4; i++) {
      int row0 = m0 + wm + i * 16 + lq * 4;
#pragma unroll
      for (int r = 0; r < 4; r++) {
        int row = row0 + r;
        float v = acc[i][j][r] + bv;
        if constexpr (MODE == 0) {
          C[(size_t)row * DM + col] = (CT)v;
        } else {
          int b = row >> 11, s = row & 2047, h = col >> 6, d = col & 63;
          C[((size_t)(b * NH + h) * SEQ + s) * HD + d] = (CT)v;
        }
      }
    }
  }
}

// ---------------------------------------------------------------------------
// Flash attention v13 (causal): the never-run clean TLP cell.
// Arithmetic (r10): ~10.1k cyc per 64-key chunk vs ~500 cyc issue at 2
// waves/SIMD -> dependent-chain (MFMA chain + 31-op fmax + exp) x too few
// waves. r5 failed it (132 true regs incl. AGPR -> 256-class -> 2/SIMD);
// r6 failed it (waves_per_eu(4,8) -> 64 regs + 12MB spill on the chain).
// v13: 32-key chunk body (r6-verified) + __launch_bounds__(256,4) (cap 128,
// natural ~111 -> no spill expected) + PERFECT wave balance: block bx owns
// pair (bx, 63-bx) as two sequential phases; in each phase all 4 waves split
// that tile's kv range [nch*w/4, nch*(w+1)/4) -> every wave ~16.25 chunks
// (old split was {0,1,32,32}). 4-way LDS merge, 26KB -> 4 blocks/CU.
// 2048 blocks (8/CU oversubscribed). XCD swizzle kept.
// ---------------------------------------------------------------------------
__global__ __launch_bounds__(256, 4) void attention_kernel(
    const bf16* __restrict__ Qc, const bf16* __restrict__ Kc,
    const bf16* __restrict__ Vt, bf16* __restrict__ ctx) {
  __shared__ float ls_o[3][2][16][64];  // partials of waves 1..3
  __shared__ float ls_ml[3][2][64];     // [{m,l}]

  int t = threadIdx.x, wave = t >> 6, lane = t & 63;
  int l31 = lane & 31, hh = lane >> 5;

  // XCD swizzle decode (bijective over 2048 blocks)
  int bid = blockIdx.x;
  int xcd = bid & 7, qq = bid >> 3;   // qq 0..255
  int g = xcd + 8 * (qq & 7);         // (b,h) group 0..63
  int bx = qq >> 3;                   // pair index 0..31
  int h = g & 15, b = g >> 4;

  const bf16* Qb = Qc + (size_t)(b * NH + h) * SEQ * HD;
  const bf16* Kb = Kc + (size_t)(b * NH + h) * SEQ * HD;
  const bf16* Vb = Vt + (size_t)(b * NH + h) * HD * SEQ;
  bf16* Cb = ctx + (size_t)b * SEQ * DM + h * HD;

#pragma unroll 1
  for (int ti = 0; ti < 2; ti++) {
    int tq = ti ? (63 - bx) : bx;
    int q0 = tq * 32;
    int nch = tq + 1;                    // 32-key chunks
    int c0 = (nch * wave) >> 2;          // this wave's chunk range
    int c1 = (nch * (wave + 1)) >> 2;

    // Q fragments: B-operand, col=query=l31, k(d) = st*16 + hh*8 + j
    bf16x8 qf[4];
#pragma unroll
    for (int st = 0; st < 4; st++)
      qf[st] = *(const bf16x8*)&Qb[(size_t)(q0 + l31) * HD + st * 16 + hh * 8];

    f32x16 o[2];
#pragma unroll
    for (int dt = 0; dt < 2; dt++)
#pragma unroll
      for (int r = 0; r < 16; r++) o[dt][r] = 0.f;
    float m_st = NEG_BIG, l_st = 0.f;

#pragma unroll 1
    for (int c = c0; c < c1; c++) {
      int kv0 = c * 32;
      // K frags: A-operand, row=key=kv0+l31, k(d) = st*16 + hh*8 + j
      bf16x8 kf[4];
#pragma unroll
      for (int st = 0; st < 4; st++)
        kf[st] =
            *(const bf16x8*)&Kb[(size_t)(kv0 + l31) * HD + st * 16 + hh * 8];
      // V^T frags: A-operand, row=d=dt*32+l31, k(key) = ks*16 + hh*8 + j
      bf16x8 vf[2][2];
#pragma unroll
      for (int dt = 0; dt < 2; dt++)
#pragma unroll
        for (int ks = 0; ks < 2; ks++)
          vf[dt][ks] = *(const bf16x8*)&Vb[(size_t)(dt * 32 + l31) * SEQ + kv0 +
                                           ks * 16 + hh * 8];

      // QK^T: s = D[key][query]; query=l31, key = kv0+(r&3)+8*(r>>2)+4*hh
      f32x16 s;
#pragma unroll
      for (int r = 0; r < 16; r++) s[r] = 0.f;
      __builtin_amdgcn_s_setprio(1);
#pragma unroll
      for (int st = 0; st < 4; st++)
        s = __builtin_amdgcn_mfma_f32_32x32x16_bf16(kf[st], qf[st], s, 0, 0, 0);
      __builtin_amdgcn_s_setprio(0);

      if (c == nch - 1) {  // diagonal chunk
        int q_g = q0 + l31;
#pragma unroll
        for (int r = 0; r < 16; r++) {
          int key = kv0 + (r & 3) + 8 * (r >> 2) + 4 * hh;
          float v = s[r] * SCALE_L2E;
          s[r] = (key > q_g) ? NEG_BIG : v;
        }
      } else {
#pragma unroll
        for (int r = 0; r < 16; r++) s[r] *= SCALE_L2E;
      }

      // online softmax: lane-local scalars, one cross-half merge each
      float mx = s[0];
#pragma unroll
      for (int r = 1; r < 16; r++) mx = fmaxf(mx, s[r]);
      mx = fmaxf(mx, __shfl_xor(mx, 32));
      float mnew = fmaxf(m_st, mx);
      float alpha = exp2f(m_st - mnew);
      m_st = mnew;
      float rs = 0.f;
#pragma unroll
      for (int r = 0; r < 16; r++) {
        float pv = exp2f(s[r] - mnew);
        s[r] = pv;
        rs += pv;
      }
      rs += __shfl_xor(rs, 32);
      l_st = l_st * alpha + rs;
#pragma unroll
      for (int dt = 0; dt < 2; dt++)
#pragma unroll
        for (int r = 0; r < 16; r++) o[dt][r] *= alpha;

      // pack P then half-swap to build PV B-frags (r6-verified mapping)
      unsigned int W[8];
#pragma unroll
      for (int w = 0; w < 8; w++) {
        unsigned int u;
        asm("v_cvt_pk_bf16_f32 %0, %1, %2"
            : "=v"(u)
            : "v"(s[2 * w]), "v"(s[2 * w + 1]));
        W[w] = u;
      }
      bf16x8 pf[2];
      {
        unsigned int x1 = hh ? W[0] : W[2];
        unsigned int x2 = hh ? W[1] : W[3];
        unsigned int x3 = hh ? W[4] : W[6];
        unsigned int x4 = hh ? W[5] : W[7];
        unsigned int y1 = (unsigned int)__shfl_xor((int)x1, 32);
        unsigned int y2 = (unsigned int)__shfl_xor((int)x2, 32);
        unsigned int y3 = (unsigned int)__shfl_xor((int)x3, 32);
        unsigned int y4 = (unsigned int)__shfl_xor((int)x4, 32);
        unsigned int* f0 = (unsigned int*)&pf[0];
        unsigned int* f1 = (unsigned int*)&pf[1];
        f0[0] = hh ? y1 : W[0];
        f0[1] = hh ? y2 : W[1];
        f0[2] = hh ? W[2] : y1;
        f0[3] = hh ? W[3] : y2;
        f1[0] = hh ? y3 : W[4];
        f1[1] = hh ? y4 : W[5];
        f1[2] = hh ? W[6] : y3;
        f1[3] = hh ? W[7] : y4;
      }

      // PV: O^T[d][query] += V^T x P
      __builtin_amdgcn_s_setprio(1);
#pragma unroll
      for (int dt = 0; dt < 2; dt++)
#pragma unroll
        for (int ks = 0; ks < 2; ks++)
          o[dt] = __builtin_amdgcn_mfma_f32_32x32x16_bf16(vf[dt][ks], pf[ks],
                                                          o[dt], 0, 0, 0);
      __builtin_amdgcn_s_setprio(0);
    }

    // 4-way merge: waves 1..3 publish partials, wave 0 merges + stores.
    if (wave != 0) {
#pragma unroll
      for (int dt = 0; dt < 2; dt++)
#pragma unroll
        for (int r = 0; r < 16; r++) ls_o[wave - 1][dt][r][lane] = o[dt][r];
      ls_ml[wave - 1][0][lane] = m_st;
      ls_ml[wave - 1][1][lane] = l_st;
    }
    __syncthreads();
    if (wave == 0) {
      float M = m_st;
      float mw[3];
#pragma unroll
      for (int w = 0; w < 3; w++) {
        mw[w] = ls_ml[w][0][lane];
        M = fmaxf(M, mw[w]);
      }
      float a0 = exp2f(m_st - M);
      float aw[3];
#pragma unroll
      for (int w = 0; w < 3; w++) aw[w] = exp2f(mw[w] - M);
      float L = l_st * a0;
#pragma unroll
      for (int w = 0; w < 3; w++) L += ls_ml[w][1][lane] * aw[w];
      float linv = 1.f / L;
      int row = q0 + l31;
#pragma unroll
      for (int dt = 0; dt < 2; dt++)
#pragma unroll
        for (int r = 0; r < 16; r += 2) {
          float va = o[dt][r] * a0;
          float vb = o[dt][r + 1] * a0;
#pragma unroll
          for (int w = 0; w < 3; w++) {
            va += ls_o[w][dt][r][lane] * aw[w];
            vb += ls_o[w][dt][r + 1][lane] * aw[w];
          }
          va *= linv;
          vb *= linv;
          unsigned int u;
          asm("v_cvt_pk_bf16_f32 %0, %1, %2" : "=v"(u) : "v"(va), "v"(vb));
          int d = dt * 32 + (r & 3) + 8 * (r >> 2) + 4 * hh;
          *(unsigned int*)&Cb[(size_t)row * DM + d] = u;
        }
    }
    __syncthreads();  // LDS reused by next tile phase
  }
}

// ---------------------------------------------------------------------------
// I/O: ALL inputs float32, output float32 (32 MB). Internals bf16.
// ws (56 MB): [0,8) 4x Wt bf16 | [8,24) Qc | [24,40) Kc | [40,56) ctx.
// d_out: V^T [0,16)MB (written by fused QKV GEMM z=2, dead after attention),
// then final f32 C (32 MB). 4 dispatches total.
// ---------------------------------------------------------------------------
extern "C" void kernel_launch(void* const* d_in, const int* in_sizes, int n_in,
                              void* d_out, int out_size, void* d_ws,
                              size_t ws_size, hipStream_t stream) {
  const float* iq = (const float*)d_in[0];
  const float* ik = (const float*)d_in[1];
  const float* iv = (const float*)d_in[2];
  const float* Wq = (const float*)d_in[3];
  const float* bq = (const float*)d_in[4];
  const float* Wk = (const float*)d_in[5];
  const float* bk = (const float*)d_in[6];
  const float* Wv = (const float*)d_in[7];
  const float* bv = (const float*)d_in[8];
  const float* Wo = (const float*)d_in[9];
  const float* bo = (const float*)d_in[10];

  char* ws = (char*)d_ws;
  const size_t MB = 1024 * 1024;
  bf16* Tq = (bf16*)(ws + 0 * MB);
  bf16* Tk = (bf16*)(ws + 2 * MB);
  bf16* Tv = (bf16*)(ws + 4 * MB);
  bf16* To = (bf16*)(ws + 6 * MB);
  bf16* Qc = (bf16*)(ws + 8 * MB);   // compact [B,H,S,64]
  bf16* Kc = (bf16*)(ws + 24 * MB);  // compact [B,H,S,64]
  bf16* Cx = (bf16*)(ws + 40 * MB);  // attention output ctx
  bf16* Vtp = (bf16*)d_out;          // V^T [B,H,64,S]

  transpose_w_kernel<<<dim3(16, 16, 4), 256, 0, stream>>>(Wq, Wk, Wv, Wo, Tq,
                                                          Tk, Tv, To);
  qkv_gemm_kernel<<<dim3(64, 8, 3), 256, 0, stream>>>(
      iq, ik, iv, Tq, Tk, Tv, bq, bk, bv, Qc, Kc, Vtp);
  attention_kernel<<<dim3(2048), 256, 0, stream>>>(Qc, Kc, Vtp, Cx);
  gemm_bias_kernel<float, 0><<<dim3(64, 8), 256, 0, stream>>>(Cx, To, bo,
                                                              (float*)d_out);
}